// Round 5
// baseline (159.941 us; speedup 1.0000x reference)
//
#include <hip/hip_runtime.h>
#include <math.h>

// Problem constants (from reference): N=100000, S=64, Q=50, P=3
#define N_Q 50
#define N_S 64
#define ROW_F2 75          // 150 floats = 75 float2 per pauli word
#define THREADS 256        // 4 waves; wave ws handles s in [16ws, 16ws+16)
#define BLK_ROWS 256       // 4 row-groups of 64; lane owns rows lane+64g
#define APAD 14            // A-window row stride: 12 floats (4 q) + 2 pad
                           //   (14*lane) mod 32 -> 2-way alias = free
#define NWIN_FULL 12       // 12 windows of 4 q + 1 tail window of 2 q

// ws layout: [0..3128) partials double[391]; [3136..3140) done-counter
#define WS_CNT_OFF 3136

__device__ __forceinline__ float softplus20(float x) {
    float z = x * 20.0f;
    return fmaxf(z, 0.0f) + log1pf(expf(-fabsf(z)));  // stable softplus
}

// Stage NF2 float2/thread of the A window into registers (coalesced-ish:
// consecutive lanes walk tile-linear -> ~11 lines/instr, not 64).
template <int NF2>
__device__ __forceinline__ void fetchA(float2 (&r)[6], const float2* __restrict__ Af2,
                                       int nbase, int tid, int f2off, int N) {
    #pragma unroll
    for (int k = 0; k < NF2; ++k) {
        int j = tid + THREADS * k;
        int row = j / NF2;
        int c2 = j - row * NF2;
        int n = nbase + row;
        if (n >= N) n = N - 1;  // clamp: duplicate row, masked in epilogue
        r[k] = Af2[(size_t)n * ROW_F2 + f2off + c2];
    }
}

template <int NF2>
__device__ __forceinline__ void writeA(const float2 (&r)[6], float* __restrict__ abuf,
                                       int tid) {
    #pragma unroll
    for (int k = 0; k < NF2; ++k) {
        int j = tid + THREADS * k;
        int row = j / NF2;
        int c2 = j - row * NF2;
        // (APAD*row + 2*c2) is even -> 8-B aligned b64 write, <=2-way banks
        *(float2*)&abuf[row * APAD + 2 * c2] = r[k];
    }
}

// One window (WQ qubits): 16 s-values x 4 row-groups per lane.
// H comes as b128 broadcasts (all lanes same addr), A as stride-14 b32.
template <int WQ>
__device__ __forceinline__ void computeWin(const float* __restrict__ abuf,
                                           const float* __restrict__ hq0,
                                           int lane, float (&prod)[4][16]) {
    #pragma unroll
    for (int qq = 0; qq < WQ; ++qq) {
        float a0[4], a1[4], a2[4];
        #pragma unroll
        for (int g = 0; g < 4; ++g) {
            const float* ap = abuf + (lane + 64 * g) * APAD + 3 * qq;
            a0[g] = ap[0]; a1[g] = ap[1]; a2[g] = ap[2];
        }
        const float4* Hq = (const float4*)(hq0 + qq * (N_S * 3));
        #pragma unroll
        for (int grp = 0; grp < 4; ++grp) {
            // 4 s-values packed: [h00 h01 h02 h10][h11 h12 h20 h21][h22 h30 h31 h32]
            float4 b0 = Hq[3*grp+0], b1 = Hq[3*grp+1], b2 = Hq[3*grp+2];
            #pragma unroll
            for (int g = 0; g < 4; ++g) {
                prod[g][4*grp+0] *= fmaf(b0.x, a0[g], fmaf(b0.y, a1[g], b0.z * a2[g]));
                prod[g][4*grp+1] *= fmaf(b0.w, a0[g], fmaf(b1.x, a1[g], b1.y * a2[g]));
                prod[g][4*grp+2] *= fmaf(b1.z, a0[g], fmaf(b1.w, a1[g], b2.x * a2[g]));
                prod[g][4*grp+3] *= fmaf(b2.y, a0[g], fmaf(b2.z, a1[g], b2.w * a2[g]));
            }
        }
    }
}

__global__ __launch_bounds__(THREADS, 2) void main_kernel(
    const float* __restrict__ A, const float* __restrict__ coeff,
    const float* __restrict__ heads_param, const float* __restrict__ hr_param,
    double* __restrict__ partials, int* __restrict__ cnt,
    float* __restrict__ out, int N) {
    __shared__ __align__(16) float hHs[N_Q * N_S * 3];      // 38400 B, [q][s][3]
    __shared__ __align__(16) float ABUF[BLK_ROWS * APAD];   // 14336 B
    __shared__ float covs[4][BLK_ROWS];                     // 4096 B
    __shared__ float hrvl[N_S];
    __shared__ double redd[4];
    __shared__ int isLast;
    // total 57.1 KB -> 2 blocks/CU

    const int tid = threadIdx.x;
    const int lane = tid & 63;
    const int ws = tid >> 6;
    const int nbase = blockIdx.x * BLK_ROWS;
    const float2* __restrict__ Af2 = (const float2*)A;

    // --- prefetch window 0 (global latency overlaps H compute below) ---
    float2 st[6];
    fetchA<6>(st, Af2, nbase, tid, 0, N);

    // --- fused H precompute: EXACT reference semantics (EPS clamp -> row
    //     may NOT sum to 1, so all three components are stored) ---
    for (int k = 0; k < 13; ++k) {
        int idx = tid + THREADS * k;
        if (idx < N_S * N_Q) {
            int q = idx >> 6, s = idx & 63;
            const float* hp = heads_param + ((size_t)s * N_Q + q) * 3;
            float sp0 = softplus20(hp[0]);
            float sp1 = softplus20(hp[1]);
            float sp2 = softplus20(hp[2]);
            float denom = fmaxf(sp0 + sp1 + sp2, 1e-12f);
            float* o = hHs + q * (N_S * 3) + s * 3;
            o[0] = sp0 / denom; o[1] = sp1 / denom; o[2] = sp2 / denom;
        }
    }
    if (tid < N_S) {
        float sp = softplus20(hr_param[tid]);
        float tot = sp;
        #pragma unroll
        for (int off = 32; off; off >>= 1) tot += __shfl_xor(tot, off);
        hrvl[tid] = (sp / fmaxf(tot, 1e-12f) + 0.001f / (float)N_S) / 1.001f;
    }
    writeA<6>(st, ABUF, tid);
    __syncthreads();

    float prod[4][16];
    #pragma unroll
    for (int g = 0; g < 4; ++g)
        #pragma unroll
        for (int i = 0; i < 16; ++i) prod[g][i] = 1.0f;

    const float* hbase = hHs + ws * 48;  // this wave's 16-s slab within [q][...]

    for (int w = 0; w < NWIN_FULL; ++w) {
        // register prefetch of window w+1: global loads issue here, land
        // during the ~1.5k-cyc compute below
        float2 nx[6];
        if (w < NWIN_FULL - 1) fetchA<6>(nx, Af2, nbase, tid, 6 * (w + 1), N);
        else                   fetchA<3>(nx, Af2, nbase, tid, 6 * (w + 1), N);

        computeWin<4>(ABUF, hbase + (4 * w) * (N_S * 3), lane, prod);
        __syncthreads();
        if (w < NWIN_FULL - 1) writeA<6>(nx, ABUF, tid);
        else                   writeA<3>(nx, ABUF, tid);
        __syncthreads();
    }
    computeWin<2>(ABUF, hbase + 48 * (N_S * 3), lane, prod);  // tail q=48,49

    // --- ratio-weighted partial covs ---
    float acc[4] = {0.0f, 0.0f, 0.0f, 0.0f};
    #pragma unroll
    for (int i = 0; i < 16; ++i) {
        float wgt = hrvl[ws * 16 + i];
        #pragma unroll
        for (int g = 0; g < 4; ++g) acc[g] = fmaf(wgt, prod[g][i], acc[g]);
    }
    #pragma unroll
    for (int g = 0; g < 4; ++g) covs[ws][lane + 64 * g] = acc[g];
    __syncthreads();

    // --- per-row finalize: wave ws owns rows 64*ws + lane ---
    {
        const int r = ws * 64 + lane;
        const int n = nbase + r;
        float cov = covs[0][r] + covs[1][r] + covs[2][r] + covs[3][r];
        float term = 0.0f;
        if (n < N) { float c = coeff[n]; term = (c * c) / cov; }
        double td = (double)term;
        #pragma unroll
        for (int off = 32; off; off >>= 1) td += __shfl_down(td, off);
        if (lane == 0) redd[ws] = td;
    }
    __syncthreads();

    if (tid == 0) {
        partials[blockIdx.x] = redd[0] + redd[1] + redd[2] + redd[3];
        __threadfence();                 // release partial
        int v = atomicAdd(cnt, 1);
        isLast = (v == (int)gridDim.x - 1);
    }
    __syncthreads();

    if (isLast) {                        // last-finishing block: final reduce
        __threadfence();                 // acquire
        double s = 0.0;
        for (int i = tid; i < (int)gridDim.x; i += THREADS) s += partials[i];
        #pragma unroll
        for (int off = 32; off; off >>= 1) s += __shfl_down(s, off);
        if (lane == 0) redd[ws] = s;
        __syncthreads();
        if (tid == 0) out[0] = (float)(redd[0] + redd[1] + redd[2] + redd[3]);
    }
}

extern "C" void kernel_launch(void* const* d_in, const int* in_sizes, int n_in,
                              void* d_out, int out_size, void* d_ws, size_t ws_size,
                              hipStream_t stream) {
    const float* A           = (const float*)d_in[0];  // [N, Q, P]
    const float* coeff       = (const float*)d_in[1];  // [N]
    const float* heads_param = (const float*)d_in[2];  // [S, Q, P]
    const float* hr_param    = (const float*)d_in[3];  // [S]
    const int N = in_sizes[1];
    const int nblocks = (N + BLK_ROWS - 1) / BLK_ROWS;  // 391

    double* partials = (double*)d_ws;
    int* cnt = (int*)((char*)d_ws + WS_CNT_OFF);
    float* out = (float*)d_out;

    hipMemsetAsync(cnt, 0, sizeof(int), stream);  // async, graph-capturable
    main_kernel<<<nblocks, THREADS, 0, stream>>>(A, coeff, heads_param, hr_param,
                                                 partials, cnt, out, N);
}